// Round 7
// baseline (101.471 us; speedup 1.0000x reference)
//
#include <hip/hip_runtime.h>

#define TOKS 65536
#define ED 64
#define NE 1024
#define CH_STRIDE 4096      // 64*64
#define B_STRIDE 262144     // 64*64*64

typedef __bf16 bf16x8 __attribute__((ext_vector_type(8)));
typedef float f32x16 __attribute__((ext_vector_type(16)));
typedef unsigned short ushort_t;
typedef unsigned int uint_t;

// ws layout:
//   efrag @ 0      : 32ct x 4ks x 64lane x 8 bf16 (hi of -2*emb) [128 KB]
//   enorm @ 131072 : 1024 f32 (np-pairwise ||e||^2, exact)        [4 KB]
//   hist  @ 135168 : 1024 i32                                     [4 KB]
//   loss  @ 139264 : 1 f64                                        [8 B]

__device__ __forceinline__ ushort_t f2bf(float x) {
    uint_t u = __float_as_uint(x);
    uint_t r = u + 0x7FFFu + ((u >> 16) & 1u);   // RNE
    return (ushort_t)(r >> 16);
}

// ---- prep E: wave per code. enorm via shfl-replicated numpy pairwise (exact
// op order: 8 accumulators, 7 sequential stride-8 adds, 3-level tree).
__global__ __launch_bounds__(256) void vq_prep_e(const float* __restrict__ emb,
                                                 ushort_t* __restrict__ efrag,
                                                 float* __restrict__ enorm,
                                                 int* __restrict__ hist,
                                                 double* __restrict__ lossAcc) {
    const int tid = threadIdx.x;
    const int w = tid >> 6, lane = tid & 63;
    const int j = blockIdx.x * 4 + w;

    const float e = emb[j * 64 + lane];
    const float sq = __fmul_rn(e, e);
    float acc = sq;
    acc = __fadd_rn(acc, __shfl_down(sq, 8, 64));
    acc = __fadd_rn(acc, __shfl_down(sq, 16, 64));
    acc = __fadd_rn(acc, __shfl_down(sq, 24, 64));
    acc = __fadd_rn(acc, __shfl_down(sq, 32, 64));
    acc = __fadd_rn(acc, __shfl_down(sq, 40, 64));
    acc = __fadd_rn(acc, __shfl_down(sq, 48, 64));
    acc = __fadd_rn(acc, __shfl_down(sq, 56, 64));
    float x = __fadd_rn(acc, __shfl_down(acc, 1, 64));
    float y = __fadd_rn(x, __shfl_down(x, 2, 64));
    float zn = __fadd_rn(y, __shfl_down(y, 4, 64));
    if (lane == 0) enorm[j] = zn;

    const ushort_t h = f2bf(-2.0f * e);
    const int ct = j >> 5, m = j & 31;
    const int ks = lane >> 4, kh = (lane >> 3) & 1, i = lane & 7;
    efrag[(size_t)((ct * 4 + ks) * 512) + (m + 32 * kh) * 8 + i] = h;

    if (blockIdx.x < 4) hist[blockIdx.x * 256 + tid] = 0;
    if (blockIdx.x == 0 && tid == 0) *lossAcc = 0.0;
}

// ---- fused: MFMA filter + exact rescore + gather/hist/loss + zq store.
// Block = 32 tokens (1 MFMA tile), 4 waves = 4 code-quarters. 2048 blocks ->
// 8 blocks/CU (launch_bounds(256,8)) for latency hiding.
__global__ __launch_bounds__(256, 8) void vq_main(
    const float* __restrict__ z,
    const ushort_t* __restrict__ efrag,
    const float* __restrict__ enorm,
    const float* __restrict__ emb,
    float* __restrict__ zq,
    float* __restrict__ out_idx,
    int* __restrict__ hist,
    double* __restrict__ lossAcc) {
    __shared__ float z_s[64][36];                 // [channel][token], pad 36
    __shared__ uint_t skey[4][32][2][3];          // [wave][token][hi][slot]
    __shared__ double wsum[4];

    const int tid = threadIdx.x;
    const int w = tid >> 6, lane = tid & 63;
    const int t0 = blockIdx.x * 32;
    const int b = t0 >> 12, hw0 = t0 & 4095;
    const float* zbase = z + (size_t)b * B_STRIDE + hw0;

    // stage z tile: 4 threads per channel x 8 floats (coalesced 128B rows)
    {
        const int c = tid >> 2, u0 = (tid & 3) * 8;
        const float* src = zbase + (size_t)c * CH_STRIDE + u0;
        float4 f0 = *(const float4*)(src);
        float4 f1 = *(const float4*)(src + 4);
        *(float4*)&z_s[c][u0] = f0;
        *(float4*)&z_s[c][u0 + 4] = f1;
    }
    __syncthreads();

    const int n = lane & 31, kh = lane >> 5;

    // B-frag: bf16(z) hi-plane
    bf16x8 zb[4];
    #pragma unroll
    for (int ks = 0; ks < 4; ++ks) {
        #pragma unroll
        for (int i = 0; i < 8; ++i) {
            union { ushort_t u; __bf16 bh; } ca;
            ca.u = f2bf(z_s[ks * 16 + kh * 8 + i][n]);
            zb[ks][i] = ca.bh;
        }
    }

    uint_t k0 = 0xFFFFFFFFu, k1 = 0xFFFFFFFFu, k2 = 0xFFFFFFFFu;
    const bf16x8* eg = (const bf16x8*)efrag;

    #pragma unroll
    for (int ct = 0; ct < 8; ++ct) {
        const int gct = w * 8 + ct;
        bf16x8 ah0 = eg[(size_t)(gct * 4 + 0) * 64 + lane];
        bf16x8 ah1 = eg[(size_t)(gct * 4 + 1) * 64 + lane];
        bf16x8 ah2 = eg[(size_t)(gct * 4 + 2) * 64 + lane];
        bf16x8 ah3 = eg[(size_t)(gct * 4 + 3) * 64 + lane];

        f32x16 acc;
        #pragma unroll
        for (int r = 0; r < 16; ++r) acc[r] = 0.25f;
        acc = __builtin_amdgcn_mfma_f32_32x32x16_bf16(ah0, zb[0], acc, 0, 0, 0);
        acc = __builtin_amdgcn_mfma_f32_32x32x16_bf16(ah1, zb[1], acc, 0, 0, 0);
        acc = __builtin_amdgcn_mfma_f32_32x32x16_bf16(ah2, zb[2], acc, 0, 0, 0);
        acc = __builtin_amdgcn_mfma_f32_32x32x16_bf16(ah3, zb[3], acc, 0, 0, 0);

        const int jb = gct * 32 + 4 * kh;
        #pragma unroll
        for (int r = 0; r < 16; ++r) {
            uint_t key = (__float_as_uint(acc[r]) & 0xFFFFFC00u)
                         | (uint_t)(jb + (r & 3) + 8 * (r >> 2));
            uint_t mx = max(k0, key);
            k2 = min(k2, max(k1, mx));
            k1 = min(k1, mx);
            k0 = min(k0, key);
        }
    }

    skey[w][n][kh][0] = k0; skey[w][n][kh][1] = k1; skey[w][n][kh][2] = k2;
    __syncthreads();

    // ---- exact rescore: 8 threads per token, 3 candidates each (24 total)
    const int t_loc = tid >> 3, cw = tid & 7;
    uint_t ck[3];
    #pragma unroll
    for (int s = 0; s < 3; ++s) ck[s] = skey[cw >> 1][t_loc][cw & 1][s];

    uint_t kmin = min(ck[0], min(ck[1], ck[2]));
    kmin = min(kmin, (uint_t)__shfl_xor((int)kmin, 1, 64));
    kmin = min(kmin, (uint_t)__shfl_xor((int)kmin, 2, 64));
    kmin = min(kmin, (uint_t)__shfl_xor((int)kmin, 4, 64));
    const float thr = __uint_as_float(kmin & 0xFFFFFC00u) + 4.0e-4f;

    // znorm: numpy pairwise, exact op order, streamed from LDS (broadcast)
    float rr[8];
    #pragma unroll
    for (int m = 0; m < 8; ++m) {
        float a = z_s[m][t_loc];
        rr[m] = __fmul_rn(a, a);
    }
    #pragma unroll
    for (int i = 8; i < 64; i += 8) {
        #pragma unroll
        for (int m = 0; m < 8; ++m) {
            float a = z_s[i + m][t_loc];
            rr[m] = __fadd_rn(rr[m], __fmul_rn(a, a));
        }
    }
    const float zn =
        __fadd_rn(__fadd_rn(__fadd_rn(rr[0], rr[1]), __fadd_rn(rr[2], rr[3])),
                  __fadd_rn(__fadd_rn(rr[4], rr[5]), __fadd_rn(rr[6], rr[7])));

    float bd = 3.4e38f; int bj = 1 << 30;
    #pragma unroll
    for (int c2 = 0; c2 < 3; ++c2) {
        const float vc = __uint_as_float(ck[c2] & 0xFFFFFC00u);
        if (vc <= thr) {                           // NaN sentinel fails -> skipped
            const int j = (int)(ck[c2] & 1023u);
            const float* e = emb + (size_t)j * 64;
            float a0 = 0.f;
            #pragma unroll
            for (int k4 = 0; k4 < 64; k4 += 4) {
                float4 e4 = *(const float4*)(e + k4);
                a0 = __fmaf_rn(z_s[k4 + 0][t_loc], e4.x, a0);
                a0 = __fmaf_rn(z_s[k4 + 1][t_loc], e4.y, a0);
                a0 = __fmaf_rn(z_s[k4 + 2][t_loc], e4.z, a0);
                a0 = __fmaf_rn(z_s[k4 + 3][t_loc], e4.w, a0);
            }
            float d = __fsub_rn(__fadd_rn(zn, enorm[j]), 2.0f * a0);
            if (d < bd || (d == bd && j < bj)) { bd = d; bj = j; }
        }
    }
    // lex-(d,j) merge across the 8-thread group -> np first-occurrence argmin
    #pragma unroll
    for (int m = 1; m < 8; m <<= 1) {
        float pd = __shfl_xor(bd, m, 64);
        int pj = __shfl_xor(bj, m, 64);
        if (pd < bd || (pd == bd && pj < bj)) { bd = pd; bj = pj; }
    }

    if (cw == 0) {
        out_idx[t0 + t_loc] = (float)bj;
        atomicAdd(&hist[bj], 1);
    }

    // gather: 8 threads/token swap z_s -> emb[bj], accumulate loss
    double ls = 0.0;
    {
        const float* e = emb + (size_t)bj * 64 + cw * 8;
        float4 ea = *(const float4*)(e);
        float4 eb = *(const float4*)(e + 4);
        float ev[8] = {ea.x, ea.y, ea.z, ea.w, eb.x, eb.y, eb.z, eb.w};
        #pragma unroll
        for (int i = 0; i < 8; ++i) {
            const int k = cw * 8 + i;
            float zv = z_s[k][t_loc];
            z_s[k][t_loc] = ev[i];                 // tile becomes z_q
            float df = ev[i] - zv;
            ls += (double)(df * df);
        }
    }
    #pragma unroll
    for (int off = 32; off > 0; off >>= 1) ls += __shfl_down(ls, off, 64);
    if (lane == 0) wsum[w] = ls;
    __syncthreads();                               // z_s fully z_q; wsum ready
    if (tid == 0)
        atomicAdd(lossAcc, wsum[0] + wsum[1] + wsum[2] + wsum[3]);

    // coalesced z_q store
    {
        const int c = tid >> 2, u0 = (tid & 3) * 8;
        float4 f0 = *(const float4*)&z_s[c][u0];
        float4 f1 = *(const float4*)&z_s[c][u0 + 4];
        float* dst = zq + (size_t)b * B_STRIDE + (size_t)c * CH_STRIDE + hw0 + u0;
        *(float4*)(dst) = f0;
        *(float4*)(dst + 4) = f1;
    }
}

__global__ __launch_bounds__(256) void vq_final(const int* __restrict__ hist,
                                                const double* __restrict__ lossAcc,
                                                float* __restrict__ outs) {
    __shared__ double red[256];
    double acc = 0.0;
    for (int j = threadIdx.x; j < NE; j += 256) {
        double em = (double)hist[j] * (1.0 / 65536.0);
        acc += em * log(em + 1e-10);
    }
    red[threadIdx.x] = acc;
    __syncthreads();
    for (int s = 128; s > 0; s >>= 1) {
        if (threadIdx.x < s) red[threadIdx.x] += red[threadIdx.x + s];
        __syncthreads();
    }
    if (threadIdx.x == 0) {
        outs[0] = (float)(1.25 * (*lossAcc) * (1.0 / 4194304.0));
        outs[1] = (float)exp(-red[0]);
    }
}

extern "C" void kernel_launch(void* const* d_in, const int* in_sizes, int n_in,
                              void* d_out, int out_size, void* d_ws, size_t ws_size,
                              hipStream_t stream) {
    const float* z = (const float*)d_in[0];
    const float* emb = (const float*)d_in[1];
    float* out = (float*)d_out;

    char* ws = (char*)d_ws;
    ushort_t* efrag = (ushort_t*)ws;
    float* enorm = (float*)(ws + 131072);
    int* hist = (int*)(ws + 135168);
    double* lossAcc = (double*)(ws + 139264);

    float* zq = out;                        // [0, 4194304)
    float* scalars = out + 4194304;         // loss, perplexity
    float* out_idx = out + 4194306;         // 65536 indices as float

    vq_prep_e<<<256, 256, 0, stream>>>(emb, efrag, enorm, hist, lossAcc);
    vq_main<<<2048, 256, 0, stream>>>(z, efrag, enorm, emb, zq, out_idx, hist, lossAcc);
    vq_final<<<1, 256, 0, stream>>>(hist, lossAcc, scalars);
}

// Round 8
// 49.157 us; speedup vs baseline: 2.0642x; 2.0642x over previous
//
#include <hip/hip_runtime.h>

#define TOKS 65536
#define ED 64
#define NE 1024
#define CH_STRIDE 4096      // 64*64
#define B_STRIDE 262144     // 64*64*64

typedef __bf16 bf16x8 __attribute__((ext_vector_type(8)));
typedef float f32x16 __attribute__((ext_vector_type(16)));
typedef unsigned short ushort_t;
typedef unsigned int uint_t;

// ws layout:
//   efrag @ 0      : 32ct x 4ks x 64lane x 8 bf16 (hi of -2*emb) [128 KB]
//   enorm @ 131072 : 1024 f32 (np-pairwise ||e||^2, exact)        [4 KB]
//   hist  @ 135168 : 1024 i32                                     [4 KB]
//   loss  @ 139264 : 1 f64                                        [8 B]

__device__ __forceinline__ ushort_t f2bf(float x) {
    uint_t u = __float_as_uint(x);
    uint_t r = u + 0x7FFFu + ((u >> 16) & 1u);   // RNE
    return (ushort_t)(r >> 16);
}

// ---- prep E: wave per code. enorm via shfl-replicated numpy pairwise (exact
// op order: 8 accumulators, 7 sequential stride-8 adds, 3-level tree).
__global__ __launch_bounds__(256) void vq_prep_e(const float* __restrict__ emb,
                                                 ushort_t* __restrict__ efrag,
                                                 float* __restrict__ enorm,
                                                 int* __restrict__ hist,
                                                 double* __restrict__ lossAcc) {
    const int tid = threadIdx.x;
    const int w = tid >> 6, lane = tid & 63;
    const int j = blockIdx.x * 4 + w;

    const float e = emb[j * 64 + lane];
    const float sq = __fmul_rn(e, e);
    float acc = sq;
    acc = __fadd_rn(acc, __shfl_down(sq, 8, 64));
    acc = __fadd_rn(acc, __shfl_down(sq, 16, 64));
    acc = __fadd_rn(acc, __shfl_down(sq, 24, 64));
    acc = __fadd_rn(acc, __shfl_down(sq, 32, 64));
    acc = __fadd_rn(acc, __shfl_down(sq, 40, 64));
    acc = __fadd_rn(acc, __shfl_down(sq, 48, 64));
    acc = __fadd_rn(acc, __shfl_down(sq, 56, 64));
    float x = __fadd_rn(acc, __shfl_down(acc, 1, 64));
    float y = __fadd_rn(x, __shfl_down(x, 2, 64));
    float zn = __fadd_rn(y, __shfl_down(y, 4, 64));
    if (lane == 0) enorm[j] = zn;

    const ushort_t h = f2bf(-2.0f * e);
    const int ct = j >> 5, m = j & 31;
    const int ks = lane >> 4, kh = (lane >> 3) & 1, i = lane & 7;
    efrag[(size_t)((ct * 4 + ks) * 512) + (m + 32 * kh) * 8 + i] = h;

    if (blockIdx.x < 4) hist[blockIdx.x * 256 + tid] = 0;
    if (blockIdx.x == 0 && tid == 0) *lossAcc = 0.0;
}

// ---- fused: MFMA filter + exact rescore + gather/hist/loss + zq store.
// Block = 32 tokens (1 MFMA tile), 4 waves = 4 code-quarters, 2048 blocks.
// launch_bounds(256,4): cap 128 VGPR (no spill); natural ~60 VGPR lets HW
// co-schedule 8 blocks/CU (VGPR step at 64 per m69).
__global__ __launch_bounds__(256, 4) void vq_main(
    const float* __restrict__ z,
    const ushort_t* __restrict__ efrag,
    const float* __restrict__ enorm,
    const float* __restrict__ emb,
    float* __restrict__ zq,
    float* __restrict__ out_idx,
    int* __restrict__ hist,
    double* __restrict__ lossAcc) {
    __shared__ float z_s[64][36];                 // [channel][token], pad 36
    __shared__ uint_t skey[4][32][2][3];          // [wave][token][hi][slot]
    __shared__ double wsum[4];

    const int tid = threadIdx.x;
    const int w = tid >> 6, lane = tid & 63;
    const int t0 = blockIdx.x * 32;
    const int b = t0 >> 12, hw0 = t0 & 4095;
    const float* zbase = z + (size_t)b * B_STRIDE + hw0;

    // stage z tile: 4 threads per channel x 8 floats (coalesced 128B rows)
    {
        const int c = tid >> 2, u0 = (tid & 3) * 8;
        const float* src = zbase + (size_t)c * CH_STRIDE + u0;
        float4 f0 = *(const float4*)(src);
        float4 f1 = *(const float4*)(src + 4);
        *(float4*)&z_s[c][u0] = f0;
        *(float4*)&z_s[c][u0 + 4] = f1;
    }
    __syncthreads();

    const int n = lane & 31, kh = lane >> 5;

    // B-frag: bf16(z) hi-plane
    bf16x8 zb[4];
    #pragma unroll
    for (int ks = 0; ks < 4; ++ks) {
        #pragma unroll
        for (int i = 0; i < 8; ++i) {
            union { ushort_t u; __bf16 bh; } ca;
            ca.u = f2bf(z_s[ks * 16 + kh * 8 + i][n]);
            zb[ks][i] = ca.bh;
        }
    }

    uint_t k0 = 0xFFFFFFFFu, k1 = 0xFFFFFFFFu, k2 = 0xFFFFFFFFu;
    const bf16x8* eg = (const bf16x8*)efrag;

    #pragma unroll
    for (int ct = 0; ct < 8; ++ct) {
        const int gct = w * 8 + ct;
        bf16x8 ah0 = eg[(size_t)(gct * 4 + 0) * 64 + lane];
        bf16x8 ah1 = eg[(size_t)(gct * 4 + 1) * 64 + lane];
        bf16x8 ah2 = eg[(size_t)(gct * 4 + 2) * 64 + lane];
        bf16x8 ah3 = eg[(size_t)(gct * 4 + 3) * 64 + lane];

        f32x16 acc;
        #pragma unroll
        for (int r = 0; r < 16; ++r) acc[r] = 0.25f;
        acc = __builtin_amdgcn_mfma_f32_32x32x16_bf16(ah0, zb[0], acc, 0, 0, 0);
        acc = __builtin_amdgcn_mfma_f32_32x32x16_bf16(ah1, zb[1], acc, 0, 0, 0);
        acc = __builtin_amdgcn_mfma_f32_32x32x16_bf16(ah2, zb[2], acc, 0, 0, 0);
        acc = __builtin_amdgcn_mfma_f32_32x32x16_bf16(ah3, zb[3], acc, 0, 0, 0);

        const int jb = gct * 32 + 4 * kh;
        #pragma unroll
        for (int r = 0; r < 16; ++r) {
            uint_t key = (__float_as_uint(acc[r]) & 0xFFFFFC00u)
                         | (uint_t)(jb + (r & 3) + 8 * (r >> 2));
            uint_t mx = max(k0, key);
            k2 = min(k2, max(k1, mx));
            k1 = min(k1, mx);
            k0 = min(k0, key);
        }
    }

    skey[w][n][kh][0] = k0; skey[w][n][kh][1] = k1; skey[w][n][kh][2] = k2;
    __syncthreads();

    // ---- exact rescore: 8 threads per token, 3 candidates each (24 total)
    const int t_loc = tid >> 3, cw = tid & 7;
    uint_t ck[3];
    #pragma unroll
    for (int s = 0; s < 3; ++s) ck[s] = skey[cw >> 1][t_loc][cw & 1][s];

    uint_t kmin = min(ck[0], min(ck[1], ck[2]));
    kmin = min(kmin, (uint_t)__shfl_xor((int)kmin, 1, 64));
    kmin = min(kmin, (uint_t)__shfl_xor((int)kmin, 2, 64));
    kmin = min(kmin, (uint_t)__shfl_xor((int)kmin, 4, 64));
    const float thr = __uint_as_float(kmin & 0xFFFFFC00u) + 4.0e-4f;

    // znorm: numpy pairwise, exact op order, streamed from LDS (broadcast)
    float rr[8];
    #pragma unroll
    for (int m = 0; m < 8; ++m) {
        float a = z_s[m][t_loc];
        rr[m] = __fmul_rn(a, a);
    }
    #pragma unroll
    for (int i = 8; i < 64; i += 8) {
        #pragma unroll
        for (int m = 0; m < 8; ++m) {
            float a = z_s[i + m][t_loc];
            rr[m] = __fadd_rn(rr[m], __fmul_rn(a, a));
        }
    }
    const float zn =
        __fadd_rn(__fadd_rn(__fadd_rn(rr[0], rr[1]), __fadd_rn(rr[2], rr[3])),
                  __fadd_rn(__fadd_rn(rr[4], rr[5]), __fadd_rn(rr[6], rr[7])));

    float bd = 3.4e38f; int bj = 1 << 30;
    #pragma unroll
    for (int c2 = 0; c2 < 3; ++c2) {
        const float vc = __uint_as_float(ck[c2] & 0xFFFFFC00u);
        if (vc <= thr) {
            const int j = (int)(ck[c2] & 1023u);
            const float* e = emb + (size_t)j * 64;
            float a0 = 0.f;
            #pragma unroll
            for (int k4 = 0; k4 < 64; k4 += 4) {
                float4 e4 = *(const float4*)(e + k4);
                a0 = __fmaf_rn(z_s[k4 + 0][t_loc], e4.x, a0);
                a0 = __fmaf_rn(z_s[k4 + 1][t_loc], e4.y, a0);
                a0 = __fmaf_rn(z_s[k4 + 2][t_loc], e4.z, a0);
                a0 = __fmaf_rn(z_s[k4 + 3][t_loc], e4.w, a0);
            }
            float d = __fsub_rn(__fadd_rn(zn, enorm[j]), 2.0f * a0);
            if (d < bd || (d == bd && j < bj)) { bd = d; bj = j; }
        }
    }
    // lex-(d,j) merge across the 8-thread group -> np first-occurrence argmin
    #pragma unroll
    for (int m = 1; m < 8; m <<= 1) {
        float pd = __shfl_xor(bd, m, 64);
        int pj = __shfl_xor(bj, m, 64);
        if (pd < bd || (pd == bd && pj < bj)) { bd = pd; bj = pj; }
    }

    if (cw == 0) {
        out_idx[t0 + t_loc] = (float)bj;
        atomicAdd(&hist[bj], 1);
    }

    // gather: 8 threads/token, INTERLEAVED channels k = cw + 8*i so the LDS
    // bank = (4*cw + t_loc) % 32 -> worst 2-way (row stride 36 floats).
    double ls = 0.0;
    {
        const float* e = emb + (size_t)bj * 64;
        #pragma unroll
        for (int i = 0; i < 8; ++i) {
            const int k = cw + 8 * i;
            float ev = e[k];
            float zv = z_s[k][t_loc];
            z_s[k][t_loc] = ev;                    // tile becomes z_q
            float df = ev - zv;
            ls += (double)(df * df);
        }
    }
    #pragma unroll
    for (int off = 32; off > 0; off >>= 1) ls += __shfl_down(ls, off, 64);
    if (lane == 0) wsum[w] = ls;
    __syncthreads();                               // z_s fully z_q; wsum ready
    if (tid == 0)
        atomicAdd(lossAcc, wsum[0] + wsum[1] + wsum[2] + wsum[3]);

    // coalesced z_q store
    {
        const int c = tid >> 2, u0 = (tid & 3) * 8;
        float4 f0 = *(const float4*)&z_s[c][u0];
        float4 f1 = *(const float4*)&z_s[c][u0 + 4];
        float* dst = zq + (size_t)b * B_STRIDE + (size_t)c * CH_STRIDE + hw0 + u0;
        *(float4*)(dst) = f0;
        *(float4*)(dst + 4) = f1;
    }
}

__global__ __launch_bounds__(256) void vq_final(const int* __restrict__ hist,
                                                const double* __restrict__ lossAcc,
                                                float* __restrict__ outs) {
    __shared__ double red[256];
    double acc = 0.0;
    for (int j = threadIdx.x; j < NE; j += 256) {
        double em = (double)hist[j] * (1.0 / 65536.0);
        acc += em * log(em + 1e-10);
    }
    red[threadIdx.x] = acc;
    __syncthreads();
    for (int s = 128; s > 0; s >>= 1) {
        if (threadIdx.x < s) red[threadIdx.x] += red[threadIdx.x + s];
        __syncthreads();
    }
    if (threadIdx.x == 0) {
        outs[0] = (float)(1.25 * (*lossAcc) * (1.0 / 4194304.0));
        outs[1] = (float)exp(-red[0]);
    }
}

extern "C" void kernel_launch(void* const* d_in, const int* in_sizes, int n_in,
                              void* d_out, int out_size, void* d_ws, size_t ws_size,
                              hipStream_t stream) {
    const float* z = (const float*)d_in[0];
    const float* emb = (const float*)d_in[1];
    float* out = (float*)d_out;

    char* ws = (char*)d_ws;
    ushort_t* efrag = (ushort_t*)ws;
    float* enorm = (float*)(ws + 131072);
    int* hist = (int*)(ws + 135168);
    double* lossAcc = (double*)(ws + 139264);

    float* zq = out;                        // [0, 4194304)
    float* scalars = out + 4194304;         // loss, perplexity
    float* out_idx = out + 4194306;         // 65536 indices as float

    vq_prep_e<<<256, 256, 0, stream>>>(emb, efrag, enorm, hist, lossAcc);
    vq_main<<<2048, 256, 0, stream>>>(z, efrag, enorm, emb, zq, out_idx, hist, lossAcc);
    vq_final<<<1, 256, 0, stream>>>(hist, lossAcc, scalars);
}